// Round 1
// baseline (1047.693 us; speedup 1.0000x reference)
//
#include <hip/hip_runtime.h>
#include <hip/hip_bf16.h>
#include <math.h>

#define T_TOK 16384
#define DM 512
#define HID 2048
#define NE 8

typedef unsigned short u16;
typedef __attribute__((ext_vector_type(4))) float f32x4;
typedef __attribute__((ext_vector_type(8))) __bf16 bf16x8;

static __device__ __forceinline__ u16 f2bf(float f) {
    __hip_bfloat16 h = __float2bfloat16(f);
    union { __hip_bfloat16 h; u16 u; } c; c.h = h; return c.u;
}

static __device__ __forceinline__ bf16x8 load_bf16x8_g(const u16* p) {
    union { uint4 u; bf16x8 b; } cv;
    cv.u = *(const uint4*)p;
    return cv.b;
}

// ---------------- x fp32 -> bf16 ----------------
__global__ __launch_bounds__(256) void cvt_x_kernel(const float* __restrict__ in,
                                                    u16* __restrict__ out) {
    int i = blockIdx.x * 256 + threadIdx.x;      // each thread: 8 elems
    const float4* p = (const float4*)in + (size_t)i * 2;
    float4 a = p[0], b = p[1];
    union { u16 s[8]; uint4 v; } r;
    r.s[0] = f2bf(a.x); r.s[1] = f2bf(a.y); r.s[2] = f2bf(a.z); r.s[3] = f2bf(a.w);
    r.s[4] = f2bf(b.x); r.s[5] = f2bf(b.y); r.s[6] = f2bf(b.z); r.s[7] = f2bf(b.w);
    *((uint4*)out + i) = r.v;
}

// ---------- transpose+convert: in fp32 [R][C] -> out bf16 [C][R], per expert (blockIdx.z) ----------
__global__ __launch_bounds__(256) void transpose_cvt(const float* __restrict__ in,
                                                     u16* __restrict__ out, int R, int C) {
    __shared__ float tile[32][33];
    const float* inp = in + (size_t)blockIdx.z * R * C;
    u16* outp = out + (size_t)blockIdx.z * R * C;
    int c0 = blockIdx.x * 32, r0 = blockIdx.y * 32;
    for (int i = threadIdx.y; i < 32; i += 8)
        tile[i][threadIdx.x] = inp[(size_t)(r0 + i) * C + c0 + threadIdx.x];
    __syncthreads();
    for (int i = threadIdx.y; i < 32; i += 8)
        outp[(size_t)(c0 + i) * R + r0 + threadIdx.x] = f2bf(tile[threadIdx.x][i]);
}

// ---------------- router: fp32 logits, top-2 softmax, expert lists ----------------
__global__ __launch_bounds__(256) void router_kernel(
    const float* __restrict__ x, const float* __restrict__ Wg,
    float* __restrict__ logits, int* __restrict__ cnt,
    int* __restrict__ tlist, float* __restrict__ wlist)
{
    int wave = threadIdx.x >> 6;
    int lane = threadIdx.x & 63;
    int t = blockIdx.x * 4 + wave;                 // one wave per token
    const float4* xp = (const float4*)(x + (size_t)t * DM + lane * 8);
    float4 a0 = xp[0], a1 = xp[1];
    float acc[NE];
#pragma unroll
    for (int e = 0; e < NE; e++) {
        const float4* wp = (const float4*)(Wg + e * DM + lane * 8);
        float4 b0 = wp[0], b1 = wp[1];
        acc[e] = a0.x*b0.x + a0.y*b0.y + a0.z*b0.z + a0.w*b0.w
               + a1.x*b1.x + a1.y*b1.y + a1.z*b1.z + a1.w*b1.w;
    }
#pragma unroll
    for (int e = 0; e < NE; e++) {
#pragma unroll
        for (int off = 32; off >= 1; off >>= 1)
            acc[e] += __shfl_xor(acc[e], off, 64);
    }
    if (lane == 0) {
        float4* lg = (float4*)(logits + (size_t)t * NE);
        lg[0] = make_float4(acc[0], acc[1], acc[2], acc[3]);
        lg[1] = make_float4(acc[4], acc[5], acc[6], acc[7]);
        // top-2 (ties -> lowest index, matching jax.lax.top_k)
        int i0 = 0; float v0 = acc[0];
#pragma unroll
        for (int e = 1; e < NE; e++) if (acc[e] > v0) { v0 = acc[e]; i0 = e; }
        int i1 = -1; float v1 = -1e30f;
#pragma unroll
        for (int e = 0; e < NE; e++) if (e != i0 && acc[e] > v1) { v1 = acc[e]; i1 = e; }
        float w0 = 1.f / (1.f + expf(v1 - v0));    // stable 2-way softmax, v1 <= v0
        float w1 = 1.f - w0;
        int p0 = atomicAdd(&cnt[i0], 1);
        tlist[i0 * T_TOK + p0] = t; wlist[i0 * T_TOK + p0] = w0;
        int p1 = atomicAdd(&cnt[i1], 1);
        tlist[i1 * T_TOK + p1] = t; wlist[i1 * T_TOK + p1] = w1;
    }
}

// ---------------- fused expert MLP: gelu(x@W1)@W2, gathered tokens ----------------
// grid: (T_TOK/64, NE), block: 512 (8 waves). Wave w owns hidden cols [w*16,w*16+16) in
// GEMM1 and out cols [w*64, w*64+64) in GEMM2. LDS: swizzled x tile + swizzled h chunk.
__global__ __launch_bounds__(512) void expert_kernel(
    const u16* __restrict__ xb, const u16* __restrict__ W1T, const u16* __restrict__ W2T,
    const int* __restrict__ cnt, const int* __restrict__ tlist, const float* __restrict__ wlist,
    float* __restrict__ out)
{
    const int e = blockIdx.y;
    const int n = cnt[e];
    const int row0 = blockIdx.x * 64;
    if (row0 >= n) return;
    const int wid  = threadIdx.x >> 6;
    const int lane = threadIdx.x & 63;
    const int l15 = lane & 15, lhi = lane >> 4;

    __shared__ char xs[64 * 1024];   // 64 rows x 512 bf16, XOR-swizzled
    __shared__ char hs[64 * 256];    // 64 rows x 128 bf16, XOR-swizzled

    // ---- stage x tile (gathered rows); invalid rows -> token 0, weight 0 later ----
#pragma unroll
    for (int i = 0; i < 8; i++) {
        int r = wid * 8 + i;
        int idx = row0 + r;
        int tok = (idx < n) ? tlist[e * T_TOK + idx] : 0;
        uint4 v = *(const uint4*)(xb + (size_t)tok * DM + lane * 8);
        *(uint4*)(xs + r * 1024 + ((lane * 16) ^ ((r & 7) << 4))) = v;
    }
    __syncthreads();

    f32x4 acc2[4][4];                // [mtile][ntile] of the 64x64 out slice
#pragma unroll
    for (int m = 0; m < 4; m++)
#pragma unroll
        for (int nt = 0; nt < 4; nt++) acc2[m][nt] = (f32x4)0.0f;

    const u16* w1e = W1T + (size_t)e * HID * DM;   // [HID][DM]
    const u16* w2e = W2T + (size_t)e * DM * HID;   // [DM][HID]

    for (int ch = 0; ch < HID / 128; ch++) {
        // ---- GEMM1: h[:, wid*16..+16) for hidden base ch*128 ----
        f32x4 acc1[4];
#pragma unroll
        for (int m = 0; m < 4; m++) acc1[m] = (f32x4)0.0f;
        const int hbase = ch * 128 + wid * 16;
        const u16* bptr = w1e + (size_t)(hbase + l15) * DM + lhi * 8;
#pragma unroll
        for (int ks = 0; ks < 16; ks++) {
            bf16x8 b = load_bf16x8_g(bptr + ks * 32);
#pragma unroll
            for (int m = 0; m < 4; m++) {
                int r = m * 16 + l15;
                int colb = (ks * 64 + lhi * 16) ^ ((r & 7) << 4);
                bf16x8 a = *(const bf16x8*)(xs + r * 1024 + colb);
                acc1[m] = __builtin_amdgcn_mfma_f32_16x16x32_bf16(a, b, acc1[m], 0, 0, 0);
            }
        }
        // ---- exact-erf GELU, cvt to bf16, store swizzled h chunk ----
#pragma unroll
        for (int m = 0; m < 4; m++) {
#pragma unroll
            for (int j = 0; j < 4; j++) {
                float v = acc1[m][j];
                float g = 0.5f * v * (1.0f + erff(v * 0.70710678118f));
                int r = m * 16 + lhi * 4 + j;
                int c = wid * 16 + l15;
                *(u16*)(hs + r * 256 + ((c * 2) ^ ((r & 7) << 4))) = f2bf(g);
            }
        }
        __syncthreads();
        // ---- GEMM2: acc2 += h_chunk @ W2[ch*128..+128, wid*64..+64) ----
#pragma unroll
        for (int ks = 0; ks < 4; ks++) {
            bf16x8 a[4];
#pragma unroll
            for (int m = 0; m < 4; m++) {
                int r = m * 16 + l15;
                int colb = (ks * 64 + lhi * 16) ^ ((r & 7) << 4);
                a[m] = *(const bf16x8*)(hs + r * 256 + colb);
            }
#pragma unroll
            for (int nt = 0; nt < 4; nt++) {
                const u16* bp = w2e + (size_t)(wid * 64 + nt * 16 + l15) * HID
                              + ch * 128 + ks * 32 + lhi * 8;
                bf16x8 b = load_bf16x8_g(bp);
#pragma unroll
                for (int m = 0; m < 4; m++)
                    acc2[m][nt] = __builtin_amdgcn_mfma_f32_16x16x32_bf16(a[m], b, acc2[m][nt], 0, 0, 0);
            }
        }
        __syncthreads();   // protect hs before next chunk rewrites it
    }

    // ---- epilogue: scale by routing weight, atomic scatter-add ----
#pragma unroll
    for (int m = 0; m < 4; m++) {
#pragma unroll
        for (int j = 0; j < 4; j++) {
            int r = m * 16 + lhi * 4 + j;
            int idx = row0 + r;
            bool ok = idx < n;
            int tok  = ok ? tlist[e * T_TOK + idx] : 0;
            float w  = ok ? wlist[e * T_TOK + idx] : 0.f;
            float* op = out + (size_t)tok * DM + wid * 64 + l15;
#pragma unroll
            for (int nt = 0; nt < 4; nt++)
                atomicAdd(op + nt * 16, acc2[m][nt][j] * w);
        }
    }
}

extern "C" void kernel_launch(void* const* d_in, const int* in_sizes, int n_in,
                              void* d_out, int out_size, void* d_ws, size_t ws_size,
                              hipStream_t stream) {
    const float* x  = (const float*)d_in[0];
    const float* Wg = (const float*)d_in[1];
    const float* W1 = (const float*)d_in[2];
    const float* W2 = (const float*)d_in[3];
    float* out = (float*)d_out;
    char* ws = (char*)d_ws;

    // ws layout (needs ~50.3 MB)
    int*   cnt   = (int*)ws;                                   // 64 B
    int*   tlist = (int*)(ws + 1024);                          // 512 KB
    float* wlist = (float*)(ws + 1024 + NE * T_TOK * 4);       // 512 KB
    u16*   xb    = (u16*)(ws + (2u << 20));                    // 16 MB
    u16*   W1T   = xb + (size_t)T_TOK * DM;                    // 16 MB
    u16*   W2T   = W1T + (size_t)NE * DM * HID;                // 16 MB

    hipMemsetAsync(cnt, 0, 64, stream);
    hipMemsetAsync(out, 0, (size_t)T_TOK * DM * sizeof(float), stream);

    cvt_x_kernel<<<T_TOK * DM / 8 / 256, 256, 0, stream>>>(x, xb);
    transpose_cvt<<<dim3(HID / 32, DM / 32, NE), dim3(32, 8), 0, stream>>>(W1, W1T, DM, HID);
    transpose_cvt<<<dim3(DM / 32, HID / 32, NE), dim3(32, 8), 0, stream>>>(W2, W2T, HID, DM);
    router_kernel<<<T_TOK / 4, 256, 0, stream>>>(x, Wg, out + (size_t)T_TOK * DM,
                                                 cnt, tlist, wlist);
    expert_kernel<<<dim3(T_TOK / 64, NE), 512, 0, stream>>>(xb, W1T, W2T,
                                                            cnt, tlist, wlist, out);
}

// Round 2
// 642.055 us; speedup vs baseline: 1.6318x; 1.6318x over previous
//
#include <hip/hip_runtime.h>
#include <hip/hip_bf16.h>
#include <math.h>

#define T_TOK 16384
#define DM 512
#define HID 2048
#define NE 8

typedef unsigned short u16;
typedef unsigned long long u64;
typedef __attribute__((ext_vector_type(4))) float f32x4;
typedef __attribute__((ext_vector_type(8))) __bf16 bf16x8;

static __device__ __forceinline__ u16 f2bf(float f) {
    __hip_bfloat16 h = __float2bfloat16(f);
    union { __hip_bfloat16 h; u16 u; } c; c.h = h; return c.u;
}

static __device__ __forceinline__ bf16x8 as_bf16x8(uint4 u) {
    union { uint4 u; bf16x8 b; } c; c.u = u; return c.b;
}

// ---------------- x fp32 -> bf16 ----------------
__global__ __launch_bounds__(256) void cvt_x_kernel(const float* __restrict__ in,
                                                    u16* __restrict__ out) {
    int i = blockIdx.x * 256 + threadIdx.x;      // each thread: 8 elems
    const float4* p = (const float4*)in + (size_t)i * 2;
    float4 a = p[0], b = p[1];
    union { u16 s[8]; uint4 v; } r;
    r.s[0] = f2bf(a.x); r.s[1] = f2bf(a.y); r.s[2] = f2bf(a.z); r.s[3] = f2bf(a.w);
    r.s[4] = f2bf(b.x); r.s[5] = f2bf(b.y); r.s[6] = f2bf(b.z); r.s[7] = f2bf(b.w);
    *((uint4*)out + i) = r.v;
}

// ---------- transpose+convert: in fp32 [R][C] -> out bf16 [C][R], per expert (blockIdx.z) ----------
__global__ __launch_bounds__(256) void transpose_cvt(const float* __restrict__ in,
                                                     u16* __restrict__ out, int R, int C) {
    __shared__ float tile[32][33];
    const float* inp = in + (size_t)blockIdx.z * R * C;
    u16* outp = out + (size_t)blockIdx.z * R * C;
    int c0 = blockIdx.x * 32, r0 = blockIdx.y * 32;
    for (int i = threadIdx.y; i < 32; i += 8)
        tile[i][threadIdx.x] = inp[(size_t)(r0 + i) * C + c0 + threadIdx.x];
    __syncthreads();
    for (int i = threadIdx.y; i < 32; i += 8)
        outp[(size_t)(c0 + i) * R + r0 + threadIdx.x] = f2bf(tile[threadIdx.x][i]);
}

// ---------------- router: fp32 logits, top-2, aggregated expert-list append ----------------
// block = 256 thr (4 waves), 64 tokens. Phase A: wave computes 16 tokens (coalesced row
// reads, shuffle-reduce). Phase B: wave 0 (lane = token) ballot-aggregates list appends:
// only 8 global atomics per block (one per expert, in parallel lanes).
__global__ __launch_bounds__(256) void router_kernel(
    const float* __restrict__ x, const float* __restrict__ Wg,
    float* __restrict__ logits, int* __restrict__ cnt,
    int* __restrict__ tlist, float* __restrict__ wlist)
{
    __shared__ int   s_sel[128];
    __shared__ float s_w[128];
    const int wave = threadIdx.x >> 6, lane = threadIdx.x & 63;
    const int tbase = blockIdx.x * 64;

    for (int i = 0; i < 16; i++) {
        int ti = wave * 16 + i;
        int t  = tbase + ti;
        const float4* xp = (const float4*)(x + (size_t)t * DM) + lane * 2;
        float4 a0 = xp[0], a1 = xp[1];
        float acc[NE];
#pragma unroll
        for (int e = 0; e < NE; e++) {
            const float4* wp = (const float4*)(Wg + e * DM) + lane * 2;
            float4 b0 = wp[0], b1 = wp[1];
            acc[e] = a0.x*b0.x + a0.y*b0.y + a0.z*b0.z + a0.w*b0.w
                   + a1.x*b1.x + a1.y*b1.y + a1.z*b1.z + a1.w*b1.w;
        }
#pragma unroll
        for (int e = 0; e < NE; e++) {
#pragma unroll
            for (int off = 32; off >= 1; off >>= 1)
                acc[e] += __shfl_xor(acc[e], off, 64);
        }
        if (lane == 0) {
            float4* lg = (float4*)(logits + (size_t)t * NE);
            lg[0] = make_float4(acc[0], acc[1], acc[2], acc[3]);
            lg[1] = make_float4(acc[4], acc[5], acc[6], acc[7]);
            int i0 = 0; float v0 = acc[0];
#pragma unroll
            for (int e = 1; e < NE; e++) if (acc[e] > v0) { v0 = acc[e]; i0 = e; }
            int i1 = -1; float v1 = -1e30f;
#pragma unroll
            for (int e = 0; e < NE; e++) if (e != i0 && acc[e] > v1) { v1 = acc[e]; i1 = e; }
            float w0 = 1.f / (1.f + __expf(v1 - v0) * 0.f + expf(v1 - v0));  // exact expf
            s_sel[ti * 2] = i0; s_sel[ti * 2 + 1] = i1;
            s_w[ti * 2] = w0;   s_w[ti * 2 + 1] = 1.f - w0;
        }
    }
    __syncthreads();
    if (wave == 0) {
        int s0 = s_sel[lane * 2], s1 = s_sel[lane * 2 + 1];
        float w0 = s_w[lane * 2], w1 = s_w[lane * 2 + 1];
        u64 A = 0, B = 0, C = 0;     // A=m0[s0], B=m0[s1], C=m1[s1]
        int myTot = 0;
#pragma unroll
        for (int e = 0; e < NE; e++) {
            u64 q0 = __ballot(s0 == e);
            u64 q1 = __ballot(s1 == e);
            if (s0 == e) A = q0;
            if (s1 == e) { B = q0; C = q1; }
            if (lane == e) myTot = __popcll(q0) + __popcll(q1);
        }
        int base = 0;
        if (lane < NE) base = atomicAdd(&cnt[lane], myTot);
        u64 below = ((u64)1 << lane) - 1;
        int b0 = __shfl(base, s0, 64);
        int b1 = __shfl(base, s1, 64);
        int t = tbase + lane;
        int slot0 = b0 + __popcll(A & below);
        int slot1 = b1 + __popcll(B) + __popcll(C & below);
        tlist[s0 * T_TOK + slot0] = t; wlist[s0 * T_TOK + slot0] = w0;
        tlist[s1 * T_TOK + slot1] = t; wlist[s1 * T_TOK + slot1] = w1;
    }
}

// ---------------- fused expert MLP v2 ----------------
// M=64 tokens/block, 8 waves. Per hidden chunk of 128:
//   GEMM1 (swapped operands: mfma(W1,x) -> lane holds 4 consecutive hidden for one token)
//   -> issue all 16 W2 fragment loads (latency hidden under GELU)
//   -> GELU + packed uint2 hs writes (double-buffered) -> ONE barrier
//   -> GEMM2: pure-register MFMA burst from prefetched W2 frags.
__global__ __launch_bounds__(512, 2) void expert_kernel(
    const u16* __restrict__ xb, const u16* __restrict__ W1T, const u16* __restrict__ W2T,
    const int* __restrict__ cnt, const int* __restrict__ tlist, const float* __restrict__ wlist,
    float* __restrict__ out)
{
    const int e = blockIdx.y;
    const int n = cnt[e];
    const int row0 = blockIdx.x * 64;
    if (row0 >= n) return;
    const int wid = threadIdx.x >> 6;
    const int lane = threadIdx.x & 63;
    const int l15 = lane & 15, lhi = lane >> 4;

    __shared__ char xs[64 * 1024];        // 64 tok x 512 bf16, XOR-swizzled 16B units
    __shared__ char hs[2][64 * 256];      // dbuf: 64 tok x 128 bf16, XOR-swizzled

    // ---- stage x tile (gathered rows) ----
#pragma unroll
    for (int i = 0; i < 8; i++) {
        int r = wid * 8 + i;
        int idx = row0 + r;
        int tok = (idx < n) ? tlist[e * T_TOK + idx] : 0;
        uint4 v = *(const uint4*)(xb + (size_t)tok * DM + lane * 8);
        *(uint4*)(xs + r * 1024 + ((lane * 16) ^ ((r & 7) << 4))) = v;
    }
    __syncthreads();

    f32x4 acc2[4][4];
#pragma unroll
    for (int m = 0; m < 4; m++)
#pragma unroll
        for (int nt = 0; nt < 4; nt++) acc2[m][nt] = (f32x4)0.0f;

    const u16* w1e = W1T + (size_t)e * HID * DM;   // [HID][DM]
    const u16* w2e = W2T + (size_t)e * DM * HID;   // [DM][HID]
    const u16* w1base = w1e + (size_t)(wid * 16 + l15) * DM + lhi * 8;
    const u16* w2base = w2e + (size_t)(wid * 64 + l15) * HID + lhi * 8;

    int xrow[4], hrow[4], swz[4];
#pragma unroll
    for (int m = 0; m < 4; m++) {
        int r = m * 16 + l15;
        xrow[m] = r * 1024;
        hrow[m] = r * 256;
        swz[m]  = (r & 7) << 4;
    }
    const int hwoff = ((wid * 32 + lhi * 8) ^ ((l15 & 7) << 4));  // hs write byte offset base (tok&7 == l15&7)

    for (int ch = 0; ch < HID / 128; ++ch) {
        // ---- GEMM1 (swapped): acc1[m] holds h^T: col=token(l15), row=hid(lhi*4+j) ----
        f32x4 acc1[4];
#pragma unroll
        for (int m = 0; m < 4; m++) acc1[m] = (f32x4)0.0f;
        const u16* bp1 = w1base + (size_t)ch * 128 * DM;
#pragma unroll
        for (int ks = 0; ks < 16; ++ks) {
            bf16x8 bw1 = *(const bf16x8*)(bp1 + ks * 32);
            int colb = ks * 64 + lhi * 16;
#pragma unroll
            for (int m = 0; m < 4; ++m) {
                bf16x8 ax = *(const bf16x8*)(xs + xrow[m] + (colb ^ swz[m]));
                acc1[m] = __builtin_amdgcn_mfma_f32_16x16x32_bf16(bw1, ax, acc1[m], 0, 0, 0);
            }
        }
        // ---- issue W2 fragment loads now; GELU below hides their L2 latency ----
        uint4 bw2[16];
        const u16* bp2 = w2base + ch * 128;
#pragma unroll
        for (int nt = 0; nt < 4; ++nt)
#pragma unroll
            for (int k2 = 0; k2 < 4; ++k2)
                bw2[nt * 4 + k2] = *(const uint4*)(bp2 + (size_t)nt * 16 * HID + k2 * 32);
        // ---- exact-erf GELU, pack 4 consecutive hidden, one uint2 LDS write per m ----
        char* hw = hs[ch & 1];
#pragma unroll
        for (int m = 0; m < 4; ++m) {
            union { ushort4 s; uint2 v; } pk;
            {
                float v0 = acc1[m][0], v1 = acc1[m][1], v2 = acc1[m][2], v3 = acc1[m][3];
                pk.s.x = f2bf(0.5f * v0 * (1.0f + erff(v0 * 0.70710678f)));
                pk.s.y = f2bf(0.5f * v1 * (1.0f + erff(v1 * 0.70710678f)));
                pk.s.z = f2bf(0.5f * v2 * (1.0f + erff(v2 * 0.70710678f)));
                pk.s.w = f2bf(0.5f * v3 * (1.0f + erff(v3 * 0.70710678f)));
            }
            *(uint2*)(hw + m * 16 * 256 + l15 * 256 + hwoff) = pk.v;
        }
        __syncthreads();   // single barrier per chunk (dbuf makes it safe)
        // ---- GEMM2: pure-register burst ----
        const char* hr = hs[ch & 1];
#pragma unroll
        for (int k2 = 0; k2 < 4; ++k2) {
            bf16x8 a[4];
            int colb = k2 * 64 + lhi * 16;
#pragma unroll
            for (int m = 0; m < 4; ++m)
                a[m] = *(const bf16x8*)(hr + hrow[m] + (colb ^ swz[m]));
#pragma unroll
            for (int nt = 0; nt < 4; ++nt) {
                bf16x8 b = as_bf16x8(bw2[nt * 4 + k2]);
#pragma unroll
                for (int m = 0; m < 4; ++m)
                    acc2[m][nt] = __builtin_amdgcn_mfma_f32_16x16x32_bf16(a[m], b, acc2[m][nt], 0, 0, 0);
            }
        }
    }

    // ---- epilogue: scale by routing weight, atomic scatter-add ----
#pragma unroll
    for (int m = 0; m < 4; m++) {
#pragma unroll
        for (int j = 0; j < 4; j++) {
            int r = m * 16 + lhi * 4 + j;
            int idx = row0 + r;
            bool ok = idx < n;
            int tok  = ok ? tlist[e * T_TOK + idx] : 0;
            float w  = ok ? wlist[e * T_TOK + idx] : 0.f;
            float* op = out + (size_t)tok * DM + wid * 64 + l15;
#pragma unroll
            for (int nt = 0; nt < 4; nt++)
                atomicAdd(op + nt * 16, acc2[m][nt][j] * w);
        }
    }
}

extern "C" void kernel_launch(void* const* d_in, const int* in_sizes, int n_in,
                              void* d_out, int out_size, void* d_ws, size_t ws_size,
                              hipStream_t stream) {
    const float* x  = (const float*)d_in[0];
    const float* Wg = (const float*)d_in[1];
    const float* W1 = (const float*)d_in[2];
    const float* W2 = (const float*)d_in[3];
    float* out = (float*)d_out;
    char* ws = (char*)d_ws;

    // ws layout (~50.3 MB)
    int*   cnt   = (int*)ws;                                   // 64 B
    int*   tlist = (int*)(ws + 1024);                          // 512 KB
    float* wlist = (float*)(ws + 1024 + NE * T_TOK * 4);       // 512 KB
    u16*   xb    = (u16*)(ws + (2u << 20));                    // 16 MB
    u16*   W1T   = xb + (size_t)T_TOK * DM;                    // 16 MB
    u16*   W2T   = W1T + (size_t)NE * DM * HID;                // 16 MB

    hipMemsetAsync(cnt, 0, 64, stream);
    hipMemsetAsync(out, 0, (size_t)T_TOK * DM * sizeof(float), stream);

    cvt_x_kernel<<<T_TOK * DM / 8 / 256, 256, 0, stream>>>(x, xb);
    transpose_cvt<<<dim3(HID / 32, DM / 32, NE), dim3(32, 8), 0, stream>>>(W1, W1T, DM, HID);
    transpose_cvt<<<dim3(DM / 32, HID / 32, NE), dim3(32, 8), 0, stream>>>(W2, W2T, HID, DM);
    router_kernel<<<T_TOK / 64, 256, 0, stream>>>(x, Wg, out + (size_t)T_TOK * DM,
                                                  cnt, tlist, wlist);
    expert_kernel<<<dim3(T_TOK / 64, NE), 512, 0, stream>>>(xb, W1T, W2T,
                                                            cnt, tlist, wlist, out);
}